// Round 8
// baseline (106.005 us; speedup 1.0000x reference)
//
#include <hip/hip_runtime.h>

#define N_NODES 10000
#define N_EDGES 320000
#define KDIM 640            // 5 * 128
#define C_OUT 128

typedef __attribute__((ext_vector_type(8))) short short8;   // 8 bf16
typedef __attribute__((ext_vector_type(4))) float floatx4;  // MFMA C/D + nt loads
typedef __attribute__((ext_vector_type(2))) unsigned int uintx2;

// ---- bf16 helpers ---------------------------------------------------------
__device__ __forceinline__ unsigned short f2bf(float f) {
    unsigned int b = __float_as_uint(f);
    b = (b + 0x7FFFu + ((b >> 16) & 1u)) >> 16;   // RNE
    return (unsigned short)b;
}
__device__ __forceinline__ unsigned int pack2(float x, float y) {
    return (unsigned int)f2bf(x) | ((unsigned int)f2bf(y) << 16);
}
__device__ __forceinline__ float2 unpack2(unsigned int u) {
    float2 r;
    r.x = __uint_as_float(u << 16);
    r.y = __uint_as_float(u & 0xFFFF0000u);
    return r;
}

// ---------------------------------------------------------------------------
// Prep kernel: one launch, three block roles.
//   [0,1250)    : h (f32) -> hb (bf16)   (nt reads; cached writes)
//   [1250,1330) : W -> Wt (128x640 bf16) transposed
//   [1330,1370) : CSR offsets via binary search over sorted src
// ---------------------------------------------------------------------------
__global__ __launch_bounds__(256) void prep(
        const float* __restrict__ h, uintx2* __restrict__ hb4,
        const float* __restrict__ W, unsigned short* __restrict__ Wt,
        const int* __restrict__ src, int* __restrict__ offsets) {
    const int bid = blockIdx.x;
    const int tid = threadIdx.x;

    if (bid < 1250) {                       // conv_h: 1250*256 = 320000 exact
        const int t = bid * 256 + tid;
        floatx4 v = __builtin_nontemporal_load(&((const floatx4*)h)[t]);
        uintx2 o;
        o.x = pack2(v.x, v.y);
        o.y = pack2(v.z, v.w);
        hb4[t] = o;                         // cached: want hb4 L2-resident
    } else if (bid < 1330) {                // conv_w transpose, 80 blocks
        __shared__ float tile[32][33];
        const int b = bid - 1250;
        const int k0 = (b % 20) * 32, o0 = (b / 20) * 32;
        const int tx = tid & 31, ty = tid >> 5;      // 32 x 8
#pragma unroll
        for (int i = 0; i < 4; ++i)
            tile[ty + 8 * i][tx] =
                __builtin_nontemporal_load(&W[(size_t)(k0 + ty + 8 * i) * C_OUT + o0 + tx]);
        __syncthreads();
#pragma unroll
        for (int i = 0; i < 4; ++i)
            Wt[(size_t)(o0 + ty + 8 * i) * KDIM + k0 + tx] = f2bf(tile[tx][ty + 8 * i]);
    } else {                                // offsets, 40 blocks
        const int n = (bid - 1330) * 256 + tid;
        if (n > N_NODES) return;
        int lo = 0, hi = N_EDGES;
        while (lo < hi) {
            int mid = (lo + hi) >> 1;
            if (src[mid] < n) lo = mid + 1; else hi = mid;
        }
        offsets[n] = lo;
    }
}

// ---------------------------------------------------------------------------
// Fused scatter + GEMM. Block = 512 threads (8 waves) = 16 nodes.
//
// Phase 1 (scatter): ONE NODE PER WAVE, 2 nodes sequentially per wave.
//   wv forced scalar via readfirstlane -> node, e, dst[e], X[e][*] are all
//   wave-uniform SGPR values; the compiler emits s_load (SMEM pipe) for
//   them: ZERO VALU/LDS/vmem cost for the per-edge metadata (rounds 4-7
//   paid 6 ops/edge on vmem, then bperm, then the LDS pipe for this).
//   Control flow is fully scalar -> no exec-mask divergence.
//   Lane l holds channels {2l, 2l+1}: gather = 1 dword/lane, 256 B/wave,
//   coalesced. Manual unroll-4 -> 4 independent s_load->gather chains.
//   Per edge: 10 v_fma + 2 unpack + 1 addr ~= 26 cyc VALU; machine total
//   ~3.4 us issue-bound + gather 82 MB from L2 ~2.4 us.
//
// Phase 2 (GEMM): out(16x128) = Rs(16x640) x Wt(128x640)^T + bias.
//   One 16x16 tile per wave; 20x mfma_f32_16x16x32_bf16; D row=quad*4+r,
//   col=lane&15 (verified rounds 3-7). out stores nontemporal.
// ---------------------------------------------------------------------------
__global__ __launch_bounds__(512, 4) void fused_spectconv(
        const unsigned int* __restrict__ h2,   // (10000, 64) uint = 2 bf16 ch
        const float* __restrict__ X,           // (320000, 5)
        const int* __restrict__ dst,
        const int* __restrict__ offsets,
        const unsigned short* __restrict__ Wt, // (128, 640) bf16
        const float* __restrict__ bias,
        float* __restrict__ out) {
    __shared__ unsigned short Rs[16][648];     // 20.25 KB

    const int tid  = threadIdx.x;
    const int wv   = __builtin_amdgcn_readfirstlane(tid >> 6);   // scalar 0..7
    const int lane = tid & 63;
    const int m0   = blockIdx.x * 16;          // 625 blocks * 16 = 10000 exact

    for (int nn = 0; nn < 2; ++nn) {
        const int node = m0 + wv * 2 + nn;     // scalar
        const int e0 = offsets[node];          // s_load
        const int e1 = offsets[node + 1];      // s_load

        float a0x=0,a0y=0, a1x=0,a1y=0, a2x=0,a2y=0, a3x=0,a3y=0, a4x=0,a4y=0;

        int e = e0;
        for (; e + 3 < e1; e += 4) {           // scalar loop, unroll 4
            const int d0 = dst[e + 0];         // s_load x4
            const int d1 = dst[e + 1];
            const int d2 = dst[e + 2];
            const int d3 = dst[e + 3];
            const unsigned int u0 = h2[(size_t)d0 * 64 + lane];  // 4 gathers
            const unsigned int u1 = h2[(size_t)d1 * 64 + lane];  // in flight
            const unsigned int u2 = h2[(size_t)d2 * 64 + lane];
            const unsigned int u3 = h2[(size_t)d3 * 64 + lane];
#pragma unroll
            for (int q = 0; q < 4; ++q) {
                const unsigned int u = (q == 0) ? u0 : (q == 1) ? u1 : (q == 2) ? u2 : u3;
                const float* Xp = X + (size_t)(e + q) * 5;       // s_loads
                const float x0 = Xp[0], x1 = Xp[1], x2 = Xp[2], x3 = Xp[3], x4 = Xp[4];
                const float2 hv = unpack2(u);
                a0x = fmaf(x0, hv.x, a0x); a0y = fmaf(x0, hv.y, a0y);
                a1x = fmaf(x1, hv.x, a1x); a1y = fmaf(x1, hv.y, a1y);
                a2x = fmaf(x2, hv.x, a2x); a2y = fmaf(x2, hv.y, a2y);
                a3x = fmaf(x3, hv.x, a3x); a3y = fmaf(x3, hv.y, a3y);
                a4x = fmaf(x4, hv.x, a4x); a4y = fmaf(x4, hv.y, a4y);
            }
        }
        for (; e < e1; ++e) {                  // scalar tail
            const int d = dst[e];
            const unsigned int u = h2[(size_t)d * 64 + lane];
            const float* Xp = X + (size_t)e * 5;
            const float x0 = Xp[0], x1 = Xp[1], x2 = Xp[2], x3 = Xp[3], x4 = Xp[4];
            const float2 hv = unpack2(u);
            a0x = fmaf(x0, hv.x, a0x); a0y = fmaf(x0, hv.y, a0y);
            a1x = fmaf(x1, hv.x, a1x); a1y = fmaf(x1, hv.y, a1y);
            a2x = fmaf(x2, hv.x, a2x); a2y = fmaf(x2, hv.y, a2y);
            a3x = fmaf(x3, hv.x, a3x); a3y = fmaf(x3, hv.y, a3y);
            a4x = fmaf(x4, hv.x, a4x); a4y = fmaf(x4, hv.y, a4y);
        }

        // Rs row write: lane -> uint at [k*128 + 2*lane], 256 B contiguous,
        // 2-way bank aliasing (free).
        const int nrel = wv * 2 + nn;
        *(unsigned int*)&Rs[nrel][0 * 128 + 2 * lane] = pack2(a0x, a0y);
        *(unsigned int*)&Rs[nrel][1 * 128 + 2 * lane] = pack2(a1x, a1y);
        *(unsigned int*)&Rs[nrel][2 * 128 + 2 * lane] = pack2(a2x, a2y);
        *(unsigned int*)&Rs[nrel][3 * 128 + 2 * lane] = pack2(a3x, a3y);
        *(unsigned int*)&Rs[nrel][4 * 128 + 2 * lane] = pack2(a4x, a4y);
    }

    __syncthreads();

    // ---- GEMM phase ----
    const int col  = lane & 15;
    const int quad = lane >> 4;
    const int c0   = wv * 16;

    floatx4 acc = {0.f, 0.f, 0.f, 0.f};
    const unsigned short* wrow = Wt + (size_t)(c0 + col) * KDIM + quad * 8;

#pragma unroll
    for (int kc = 0; kc < 20; ++kc) {
        const short8 af = *(const short8*)&Rs[col][kc * 32 + quad * 8];
        const short8 bf = *(const short8*)(wrow + kc * 32);
        acc = __builtin_amdgcn_mfma_f32_16x16x32_bf16(af, bf, acc, 0, 0, 0);
    }

    const float bv = bias[c0 + col];
#pragma unroll
    for (int r = 0; r < 4; ++r) {
        const int m = m0 + quad * 4 + r;
        __builtin_nontemporal_store(acc[r] + bv, &out[(size_t)m * C_OUT + c0 + col]);
    }
}

// ---------------------------------------------------------------------------
extern "C" void kernel_launch(void* const* d_in, const int* in_sizes, int n_in,
                              void* d_out, int out_size, void* d_ws, size_t ws_size,
                              hipStream_t stream) {
    const float* h      = (const float*)d_in[0];   // (10000,128)
    const float* X      = (const float*)d_in[1];   // (320000,5)
    const int*   ei     = (const int*)d_in[2];     // (2,320000)
    const float* weight = (const float*)d_in[4];   // (5,128,128) == W(640,128)
    const float* bias   = (const float*)d_in[5];   // (128,)
    float* out = (float*)d_out;

    const int* src = ei;
    const int* dst = ei + N_EDGES;

    // Workspace: offsets [0,64KB) | hb bf16 [64KB, +2.56MB) | Wt bf16 [+4MB,..)
    char* wsb = (char*)d_ws;
    int*            offsets = (int*)wsb;
    uintx2*         hb4     = (uintx2*)(wsb + (64 << 10));
    unsigned short* Wtb     = (unsigned short*)(wsb + (64 << 10) + (4 << 20));

    prep<<<1370, 256, 0, stream>>>(h, hb4, weight, Wtb, src, offsets);
    fused_spectconv<<<625, 512, 0, stream>>>((const unsigned int*)hb4, X, dst,
                                             offsets, Wtb, bias, out);
}

// Round 9
// 100.185 us; speedup vs baseline: 1.0581x; 1.0581x over previous
//
#include <hip/hip_runtime.h>

#define N_NODES 10000
#define N_EDGES 320000
#define KDIM 640            // 5 * 128
#define C_OUT 128

typedef __attribute__((ext_vector_type(8))) short short8;   // 8 bf16
typedef __attribute__((ext_vector_type(4))) float floatx4;  // MFMA C/D + nt loads
typedef __attribute__((ext_vector_type(2))) unsigned int uintx2;

// ---- bf16 helpers ---------------------------------------------------------
__device__ __forceinline__ unsigned short f2bf(float f) {
    unsigned int b = __float_as_uint(f);
    b = (b + 0x7FFFu + ((b >> 16) & 1u)) >> 16;   // RNE
    return (unsigned short)b;
}
__device__ __forceinline__ unsigned int pack2(float x, float y) {
    return (unsigned int)f2bf(x) | ((unsigned int)f2bf(y) << 16);
}
__device__ __forceinline__ float2 unpack2(unsigned int u) {
    float2 r;
    r.x = __uint_as_float(u << 16);
    r.y = __uint_as_float(u & 0xFFFF0000u);
    return r;
}

// ---------------------------------------------------------------------------
// Prep kernel: one launch, three block roles.
//   [0,1250)    : h (f32) -> hb (bf16)   (nt reads; cached writes)
//   [1250,1330) : W -> Wt (128x640 bf16) transposed
//   [1330,1370) : CSR offsets via binary search over sorted src
// ---------------------------------------------------------------------------
__global__ __launch_bounds__(256) void prep(
        const float* __restrict__ h, uintx2* __restrict__ hb4,
        const float* __restrict__ W, unsigned short* __restrict__ Wt,
        const int* __restrict__ src, int* __restrict__ offsets) {
    const int bid = blockIdx.x;
    const int tid = threadIdx.x;

    if (bid < 1250) {                       // conv_h: 1250*256 = 320000 exact
        const int t = bid * 256 + tid;
        floatx4 v = __builtin_nontemporal_load(&((const floatx4*)h)[t]);
        uintx2 o;
        o.x = pack2(v.x, v.y);
        o.y = pack2(v.z, v.w);
        hb4[t] = o;                         // cached: want hb4 L2-resident
    } else if (bid < 1330) {                // conv_w transpose, 80 blocks
        __shared__ float tile[32][33];
        const int b = bid - 1250;
        const int k0 = (b % 20) * 32, o0 = (b / 20) * 32;
        const int tx = tid & 31, ty = tid >> 5;      // 32 x 8
#pragma unroll
        for (int i = 0; i < 4; ++i)
            tile[ty + 8 * i][tx] =
                __builtin_nontemporal_load(&W[(size_t)(k0 + ty + 8 * i) * C_OUT + o0 + tx]);
        __syncthreads();
#pragma unroll
        for (int i = 0; i < 4; ++i)
            Wt[(size_t)(o0 + ty + 8 * i) * KDIM + k0 + tx] = f2bf(tile[tx][ty + 8 * i]);
    } else {                                // offsets, 40 blocks
        const int n = (bid - 1330) * 256 + tid;
        if (n > N_NODES) return;
        int lo = 0, hi = N_EDGES;
        while (lo < hi) {
            int mid = (lo + hi) >> 1;
            if (src[mid] < n) lo = mid + 1; else hi = mid;
        }
        offsets[n] = lo;
    }
}

// ---------------------------------------------------------------------------
// Fused scatter + GEMM. Block = 512 threads (8 waves) = 16 nodes.
//
// Phase 1 (scatter): one node per wave, 2 nodes sequentially (r8 structure:
//   scalar e/dst/X via s_load, zero per-edge VALU/LDS/vmem metadata cost).
//   Lane l = channels {2l,2l+1}; gather = 1 dword/lane (256 B/wave,
//   coalesced). Unroll 8 -> 8 independent gathers in flight.
//
// Phase 2 (GEMM): out(16x128) = Rs(16x640) x Wt(128x640)^T + bias.
//   NEW (round 9): Bs staged per 64-k chunk in LDS with COALESCED loads
//   (2x dwordx4/thread, 4 L2-requests/instr). Rounds 4-8 read B-frags
//   directly from global Wt: 16 strided 64B requests per instr, 1.6M L2
//   requests total -> request-rate bound; this is the suspected ~invariant
//   plateau term. B-frags now ds_read_b128 from Bs (pitch 68 -> <=2-way
//   bank aliasing = free). 20 MFMA/wave unchanged; D row=quad*4+r,
//   col=lane&15 (verified rounds 3-8).
// ---------------------------------------------------------------------------
__global__ __launch_bounds__(512, 4) void fused_spectconv(
        const unsigned int* __restrict__ h2,   // (10000, 64) uint = 2 bf16 ch
        const float* __restrict__ X,           // (320000, 5)
        const int* __restrict__ dst,
        const int* __restrict__ offsets,
        const unsigned short* __restrict__ Wt, // (128, 640) bf16
        const float* __restrict__ bias,
        float* __restrict__ out) {
    __shared__ unsigned short Rs[16][648];     // 20.25 KB
    __shared__ unsigned short Bs[128][68];     // 17.0 KB  (total 37.25 KB)

    const int tid  = threadIdx.x;
    const int wv   = __builtin_amdgcn_readfirstlane(tid >> 6);   // scalar 0..7
    const int lane = tid & 63;
    const int m0   = blockIdx.x * 16;          // 625 blocks * 16 = 10000 exact

    for (int nn = 0; nn < 2; ++nn) {
        const int node = m0 + wv * 2 + nn;     // scalar
        const int e0 = offsets[node];          // s_load
        const int e1 = offsets[node + 1];      // s_load

        float a0x=0,a0y=0, a1x=0,a1y=0, a2x=0,a2y=0, a3x=0,a3y=0, a4x=0,a4y=0;

        int e = e0;
        for (; e + 7 < e1; e += 8) {           // scalar loop, unroll 8
            int d[8];
            unsigned int u[8];
#pragma unroll
            for (int q = 0; q < 8; ++q) d[q] = dst[e + q];        // s_loads
#pragma unroll
            for (int q = 0; q < 8; ++q)
                u[q] = h2[(size_t)d[q] * 64 + lane];              // 8 gathers in flight
#pragma unroll
            for (int q = 0; q < 8; ++q) {
                const float* Xp = X + (size_t)(e + q) * 5;        // s_loads
                const float x0 = Xp[0], x1 = Xp[1], x2 = Xp[2], x3 = Xp[3], x4 = Xp[4];
                const float2 hv = unpack2(u[q]);
                a0x = fmaf(x0, hv.x, a0x); a0y = fmaf(x0, hv.y, a0y);
                a1x = fmaf(x1, hv.x, a1x); a1y = fmaf(x1, hv.y, a1y);
                a2x = fmaf(x2, hv.x, a2x); a2y = fmaf(x2, hv.y, a2y);
                a3x = fmaf(x3, hv.x, a3x); a3y = fmaf(x3, hv.y, a3y);
                a4x = fmaf(x4, hv.x, a4x); a4y = fmaf(x4, hv.y, a4y);
            }
        }
        for (; e < e1; ++e) {                  // scalar tail
            const int d = dst[e];
            const unsigned int u = h2[(size_t)d * 64 + lane];
            const float* Xp = X + (size_t)e * 5;
            const float x0 = Xp[0], x1 = Xp[1], x2 = Xp[2], x3 = Xp[3], x4 = Xp[4];
            const float2 hv = unpack2(u);
            a0x = fmaf(x0, hv.x, a0x); a0y = fmaf(x0, hv.y, a0y);
            a1x = fmaf(x1, hv.x, a1x); a1y = fmaf(x1, hv.y, a1y);
            a2x = fmaf(x2, hv.x, a2x); a2y = fmaf(x2, hv.y, a2y);
            a3x = fmaf(x3, hv.x, a3x); a3y = fmaf(x3, hv.y, a3y);
            a4x = fmaf(x4, hv.x, a4x); a4y = fmaf(x4, hv.y, a4y);
        }

        // Rs row write: lane -> uint at [k*128 + 2*lane]; pitch 648 shorts
        // -> b128/b32 accesses tile all 32 banks at exactly 2-way (free).
        const int nrel = wv * 2 + nn;
        *(unsigned int*)&Rs[nrel][0 * 128 + 2 * lane] = pack2(a0x, a0y);
        *(unsigned int*)&Rs[nrel][1 * 128 + 2 * lane] = pack2(a1x, a1y);
        *(unsigned int*)&Rs[nrel][2 * 128 + 2 * lane] = pack2(a2x, a2y);
        *(unsigned int*)&Rs[nrel][3 * 128 + 2 * lane] = pack2(a3x, a3y);
        *(unsigned int*)&Rs[nrel][4 * 128 + 2 * lane] = pack2(a4x, a4y);
    }

    __syncthreads();                           // Rs ready

    // ---- GEMM phase ----
    const int col  = lane & 15;
    const int quad = lane >> 4;
    const int c0   = wv * 16;

    floatx4 acc = {0.f, 0.f, 0.f, 0.f};

#pragma unroll
    for (int chunk = 0; chunk < 10; ++chunk) {
        if (chunk) __syncthreads();            // Bs consumed by prev chunk
        // Stage Bs: 128 rows x 64 bf16 = 1024 x 16B chunks, 2/thread,
        // coalesced (8 consecutive threads = 128 B of one Wt row).
#pragma unroll
        for (int r = 0; r < 2; ++r) {
            const int c = r * 512 + tid;
            const int row = c >> 3, c8 = c & 7;
            *(short8*)&Bs[row][c8 * 8] =
                *(const short8*)(Wt + (size_t)row * KDIM + chunk * 64 + c8 * 8);
        }
        __syncthreads();                       // Bs ready

#pragma unroll
        for (int hh = 0; hh < 2; ++hh) {
            const short8 af = *(const short8*)&Rs[col][chunk * 64 + hh * 32 + quad * 8];
            const short8 bf = *(const short8*)&Bs[c0 + col][hh * 32 + quad * 8];
            acc = __builtin_amdgcn_mfma_f32_16x16x32_bf16(af, bf, acc, 0, 0, 0);
        }
    }

    const float bv = bias[c0 + col];
#pragma unroll
    for (int r = 0; r < 4; ++r) {
        const int m = m0 + quad * 4 + r;
        __builtin_nontemporal_store(acc[r] + bv, &out[(size_t)m * C_OUT + c0 + col]);
    }
}

// ---------------------------------------------------------------------------
extern "C" void kernel_launch(void* const* d_in, const int* in_sizes, int n_in,
                              void* d_out, int out_size, void* d_ws, size_t ws_size,
                              hipStream_t stream) {
    const float* h      = (const float*)d_in[0];   // (10000,128)
    const float* X      = (const float*)d_in[1];   // (320000,5)
    const int*   ei     = (const int*)d_in[2];     // (2,320000)
    const float* weight = (const float*)d_in[4];   // (5,128,128) == W(640,128)
    const float* bias   = (const float*)d_in[5];   // (128,)
    float* out = (float*)d_out;

    const int* src = ei;
    const int* dst = ei + N_EDGES;

    // Workspace: offsets [0,64KB) | hb bf16 [64KB, +2.56MB) | Wt bf16 [+4MB,..)
    char* wsb = (char*)d_ws;
    int*            offsets = (int*)wsb;
    uintx2*         hb4     = (uintx2*)(wsb + (64 << 10));
    unsigned short* Wtb     = (unsigned short*)(wsb + (64 << 10) + (4 << 20));

    prep<<<1370, 256, 0, stream>>>(h, hb4, weight, Wtb, src, offsets);
    fused_spectconv<<<625, 512, 0, stream>>>((const unsigned int*)hb4, X, dst,
                                             offsets, Wtb, bias, out);
}